// Round 7
// baseline (883.871 us; speedup 1.0000x reference)
//
#include <hip/hip_runtime.h>

// ---------------------------------------------------------------------------
// RPN forward, MI355X. Only batch element 7 contributes to the output.
// conv3x3 (8 cin-split partials, 2 waves/block x 32cin, 2px x 16oc tile) ->
// reduce+leaky -> 1x1 heads -> decode/score/key -> O(N^2) rank sort ->
// top-6000 -> NMS bitmask (reference's yy2=max bug replicated) ->
// word-serial single-wave scan with STATIC speculative row prefetch ->
// 300x4 boxes. Deterministic fp32 everywhere (no float atomics).
// ---------------------------------------------------------------------------

#define NPIX 2500      // 50*50
#define NANCH 22500    // 2500*9
#define NKEY 22528     // NANCH padded to 88*256 (sentinel tail)
#define PRE 6000
#define MASKW 94       // ceil(6000/64) usable words
#define MW 96          // storage stride in words
#define JCHUNK 1536    // j-chunk for mask kernel (24 words)
#define CS 8           // cin splits stored (each block fuses 2 waves x 32 cin)
#define SPEC 16        // static speculative row-prefetch slots in scan

// ---------------- conv 3x3 partials: 2 waves/block, 2px x 16oc per lane ----
// grid (32 ocGroups, 20 pixel tiles, 8 cin groups), block 128 (2 waves).
// Wave w handles cin [z*64 + w*32, +32); LDS combine (deterministic w0+w1).
// 5120 wg x 2 waves = 40 waves/CU supply (cap 32) to hide s_load latency.
__global__ __launch_bounds__(128) void conv3x3_part(
    const float* __restrict__ x,    // batch-7 base (512,50,50)
    const float* __restrict__ wt,   // (512,512,3,3)
    float* __restrict__ part)       // (CS,512,2500)
{
    __shared__ float sAcc[32][64];               // 8 KB
    const int tid  = threadIdx.x;
    const int lane = tid & 63;
    const int wv   = tid >> 6;                   // 0..1
    const int tile = blockIdx.y;                 // 0..19
    const int ocb  = blockIdx.x * 16;
    const int cing = blockIdx.z * 64 + wv * 32;

    const int p0 = tile * 64 + lane;             // < 1280 always
    const int p1 = p0 + 1280;
    const bool act1 = (p1 < NPIX);
    const int p1c = act1 ? p1 : (NPIX - 1);

    int   soff[18];
    float mk[18];
    {
        const int hh0 = p0 / 50,  ww0 = p0 - hh0 * 50;
        const int hh1 = p1c / 50, ww1 = p1c - hh1 * 50;
        #pragma unroll
        for (int r = 0; r < 3; ++r) {
            #pragma unroll
            for (int c = 0; c < 3; ++c) {
                int gr = hh0 + r - 1, gc = ww0 + c - 1;
                bool ok = (gr >= 0) & (gr < 50) & (gc >= 0) & (gc < 50);
                soff[r * 3 + c] = ok ? (gr * 50 + gc) : 0;
                mk[r * 3 + c]   = ok ? 1.0f : 0.0f;
                gr = hh1 + r - 1; gc = ww1 + c - 1;
                ok = (gr >= 0) & (gr < 50) & (gc >= 0) & (gc < 50);
                soff[9 + r * 3 + c] = ok ? (gr * 50 + gc) : 0;
                mk[9 + r * 3 + c]   = ok ? 1.0f : 0.0f;
            }
        }
    }

    float acc0[16], acc1[16];
    #pragma unroll
    for (int o = 0; o < 16; ++o) { acc0[o] = 0.f; acc1[o] = 0.f; }

    for (int cin = 0; cin < 32; ++cin) {
        const float* xp = x + (size_t)(cing + cin) * NPIX;
        float v[18];
        #pragma unroll
        for (int k = 0; k < 18; ++k)
            v[k] = xp[soff[k]] * mk[k];
        const float* wbase = wt + ((size_t)ocb * 512 + (cing + cin)) * 9;
        #pragma unroll
        for (int o = 0; o < 16; ++o) {
            const float* w = wbase + (size_t)o * 4608;  // wave-uniform -> s_load
            #pragma unroll
            for (int t = 0; t < 9; ++t) {
                acc0[o] = fmaf(w[t], v[t],     acc0[o]);
                acc1[o] = fmaf(w[t], v[9 + t], acc1[o]);
            }
        }
    }

    if (wv == 1) {
        #pragma unroll
        for (int o = 0; o < 16; ++o) {
            sAcc[o][lane]      = acc0[o];
            sAcc[16 + o][lane] = acc1[o];
        }
    }
    __syncthreads();
    if (wv == 0) {
        float* dst = part + ((size_t)blockIdx.z * 512 + ocb) * NPIX;
        #pragma unroll
        for (int o = 0; o < 16; ++o) {
            const float r0 = acc0[o] + sAcc[o][lane];        // deterministic w0+w1
            dst[(size_t)o * NPIX + p0] = r0;
            if (act1) {
                const float r1 = acc1[o] + sAcc[16 + o][lane];
                dst[(size_t)o * NPIX + p1] = r1;
            }
        }
    }
}

// ---------------- reduce partials + bias + leaky ---------------------------
__global__ __launch_bounds__(256) void reduce_leaky(
    const float* __restrict__ part, const float* __restrict__ bias,
    float* __restrict__ feat)
{
    const int i = blockIdx.x * 256 + threadIdx.x;
    if (i >= 512 * NPIX) return;
    const int oc = i / NPIX;
    float s = part[i];
    #pragma unroll
    for (int k = 1; k < CS; ++k)
        s += part[(size_t)k * 512 * NPIX + i];
    s += bias[oc];
    s = (s >= 0.f) ? s : 0.01f * s;
    feat[i] = s;
}

// ---------------- 1x1 heads: 4-wave cin split + LDS tree reduce ------------
__global__ __launch_bounds__(256) void conv1x1_heads(
    const float* __restrict__ feat,
    const float* __restrict__ rw, const float* __restrict__ rb,
    const float* __restrict__ cw, const float* __restrict__ cb,
    float* __restrict__ regcls)   // (54, 2500)
{
    __shared__ float sAcc[3][18][64];
    const int tid  = threadIdx.x;
    const int lane = tid & 63;
    const int wv   = tid >> 6;
    const int pix0 = blockIdx.x * 64 + lane;
    const bool act = (pix0 < NPIX);
    const int pix  = act ? pix0 : (NPIX - 1);
    const int chunk = blockIdx.y;
    const float* wb; const float* bb; int ocbase;
    if (chunk == 0)      { wb = rw;            bb = rb;      ocbase = 0;  }
    else if (chunk == 1) { wb = rw + 18 * 512; bb = rb + 18; ocbase = 18; }
    else                 { wb = cw;            bb = cb;      ocbase = 36; }

    float acc[18];
    #pragma unroll
    for (int k = 0; k < 18; ++k) acc[k] = 0.f;

    const int c0 = wv * 128;
    for (int cin = c0; cin < c0 + 128; ++cin) {
        const float v = feat[(size_t)cin * NPIX + pix];
        #pragma unroll
        for (int k = 0; k < 18; ++k)
            acc[k] = fmaf(wb[k * 512 + cin], v, acc[k]);
    }
    if (wv > 0) {
        #pragma unroll
        for (int k = 0; k < 18; ++k) sAcc[wv - 1][k][lane] = acc[k];
    }
    __syncthreads();
    if (wv == 0 && act) {
        #pragma unroll
        for (int k = 0; k < 18; ++k) {
            float s = acc[k];
            s += sAcc[0][k][lane];
            s += sAcc[1][k][lane];
            s += sAcc[2][k][lane];
            regcls[(size_t)(ocbase + k) * NPIX + pix] = s + bb[k];
        }
    }
}

// ---------------- decode: anchors, softmax score, sortable key -------------
__global__ __launch_bounds__(256) void decodeK(
    const float* __restrict__ regcls,
    float4* __restrict__ boxes,
    unsigned long long* __restrict__ keys)
{
    const int i = blockIdx.x * 256 + threadIdx.x;
    if (i >= NANCH) {
        if (i < NKEY) keys[i] = 0xFFFFFFFFFFFFFFFFull;  // sentinel: > all keys
        return;
    }
    const int pos = i / 9;
    const int a   = i - pos * 9;
    const int hh  = pos / 50;
    const int wwp = pos - hh * 50;
    const int r = a / 3, s = a - r * 3;

    const float base_s[3] = {128.f, 256.f, 512.f};
    const float sq [3] = {0.70710678118654752440f, 1.0f, 1.41421356237309504880f};
    const float sqi[3] = {1.41421356237309504880f, 1.0f, 0.70710678118654752440f};
    const float hs = base_s[s] * sq[r];
    const float ws = base_s[s] * sqi[r];
    const float cx = (float)(hh * 16 + 8);    // cx indexed by h (reference quirk)
    const float cy = (float)(wwp * 16 + 8);
    const float ax = cx - ws * 0.5f;
    const float ay = cy - hs * 0.5f;

    const float pr0 = regcls[(size_t)(a * 4 + 0) * NPIX + pos];
    const float pr1 = regcls[(size_t)(a * 4 + 1) * NPIX + pos];
    const float pr2 = regcls[(size_t)(a * 4 + 2) * NPIX + pos];
    const float pr3 = regcls[(size_t)(a * 4 + 3) * NPIX + pos];
    const float c0  = regcls[(size_t)(36 + a * 2 + 0) * NPIX + pos];
    const float c1  = regcls[(size_t)(36 + a * 2 + 1) * NPIX + pos];

    const float m  = fmaxf(c0, c1);
    const float e0 = expf(c0 - m);
    const float e1 = expf(c1 - m);
    const float score = e1 / (e0 + e1);

    const float t0 = pr0 + ax;
    const float t1 = pr1 + ay;
    const float hi = 799.0f;
    const float rx1 = fminf(fmaxf(t0, 0.f), hi);
    const float ry1 = fminf(fmaxf(t1, 0.f), hi);
    const float rx2 = fminf(fmaxf((t0 + pr2) + ws, 0.f), hi);
    const float ry2 = fminf(fmaxf((t1 + pr3) + hs, 0.f), hi);
    const float bw = pr2 + ws;
    const float bh = pr3 + hs;
    const bool valid = (bw >= 16.f) && (bh >= 16.f);
    const float sc = valid ? score : -__builtin_inff();

    unsigned u = __float_as_uint(sc);
    u = (u & 0x80000000u) ? ~u : (u | 0x80000000u);  // monotone ascending map
    const unsigned k32 = ~u;                          // descending score
    keys[i]  = ((unsigned long long)k32 << 32) | (unsigned)i;  // tie: asc index
    boxes[i] = make_float4(rx1, ry1, rx2, ry2);
}

// ---------------- O(N^2) rank (stable argsort position) --------------------
__global__ __launch_bounds__(256) void rankK(
    const unsigned long long* __restrict__ keys, int* __restrict__ rank)
{
    const int i = blockIdx.x * 256 + threadIdx.x;
    const unsigned long long my = (i < NANCH) ? keys[i] : 0ull;
    const unsigned long long* kj = keys + blockIdx.y * 2816;
    int cnt = 0;
    for (int t = 0; t < 2816; t += 8) {
        #pragma unroll
        for (int q = 0; q < 8; ++q)
            cnt += (kj[t + q] < my) ? 1 : 0;
    }
    if (i < NANCH) atomicAdd(&rank[i], cnt);
}

__global__ __launch_bounds__(256) void scatterK(
    const float4* __restrict__ boxes, const int* __restrict__ rank,
    float4* __restrict__ sboxes)
{
    const int i = blockIdx.x * 256 + threadIdx.x;
    if (i < NANCH) {
        const int r = rank[i];
        if (r < PRE) sboxes[r] = boxes[i];
    }
}

// ---------------- NMS suppression bitmask (reference bug replicated) -------
__global__ __launch_bounds__(256) void nmsMaskK(
    const float4* __restrict__ sb, unsigned long long* __restrict__ mask)
{
    __shared__ float sx1[JCHUNK], sy1[JCHUNK], sx2[JCHUNK], sy2[JCHUNK], sar[JCHUNK];
    const int tid = threadIdx.x;
    const int jbase = blockIdx.y * JCHUNK;
    for (int t = tid; t < JCHUNK; t += 256) {
        const int j = jbase + t;
        if (j < PRE) {
            const float4 b = sb[j];
            sx1[t] = b.x; sy1[t] = b.y; sx2[t] = b.z; sy2[t] = b.w;
            sar[t] = (b.z - b.x + 1.f) * (b.w - b.y + 1.f);
        } else {
            sx1[t] = 0.f; sy1[t] = 0.f; sx2[t] = -1.f; sy2[t] = 0.f; sar[t] = 0.f;
        }
    }
    __syncthreads();
    const int i = blockIdx.x * 16 + (tid >> 4);
    const float4 bi = sb[i];
    const float x1 = bi.x, y1 = bi.y, x2 = bi.z, y2 = bi.w;
    const float ar = (x2 - x1 + 1.f) * (y2 - y1 + 1.f);
    for (int w = (tid & 15); w < 24; w += 16) {
        unsigned long long bits = 0ull;
        const int l0 = w * 64;
        for (int u = 0; u < 64; ++u) {
            const int j = jbase + l0 + u;
            if (j > i && j < PRE) {
                const int l = l0 + u;
                const float xx1 = fmaxf(x1, sx1[l]);
                const float yy1 = fmaxf(y1, sy1[l]);
                const float xx2 = fminf(x2, sx2[l]);
                const float yy2 = fmaxf(y2, sy2[l]);        // reference bug: max
                const float wv = fmaxf(0.f, xx2 - xx1 + 1.f);
                const float hv = fmaxf(0.f, yy2 - yy1 + 1.f);
                const float inter = wv * hv;
                const float ov = inter / ((ar + sar[l]) - inter);  // precise div
                if (ov > 0.7f) bits |= (1ull << u);
            }
        }
        mask[(size_t)i * MW + blockIdx.y * 24 + w] = bits;
    }
}

// ---------------- word-serial NMS scan + output (single wave) --------------
// Lane l holds remv words l and 64+l in registers. Per 64-candidate block g:
// diag word prefetched one block ahead; up to SPEC candidate rows prefetched
// via FULLY STATIC unrolled loads (promoted to registers, issued in one
// batch). Every kept bit is among the initial candidates (cur only grows),
// so slot matching by unrolled equality covers all but >SPEC overflow.
__global__ __launch_bounds__(64) void nmsScanOutK(
    const unsigned long long* __restrict__ mask,
    const float4* __restrict__ sb,
    float* __restrict__ out)
{
    __shared__ int sKept[300];
    __shared__ unsigned long long sKeepW[MASKW];
    const int lane = threadIdx.x;

    unsigned long long rem0 = 0ull, rem1 = 0ull;   // lane l: words l, 64+l
    int cnt = 0;
    int done = 0;

    unsigned long long diag = mask[(size_t)lane * MW + 0];   // block 0 diag

    for (int g = 0; g < MASKW && !done; ++g) {
        unsigned long long diag_next = 0ull;
        if (g + 1 < MASKW) {
            const int r2 = (g + 1) * 64 + lane;
            if (r2 < PRE) diag_next = mask[(size_t)r2 * MW + (g + 1)];
        }
        unsigned long long cur;
        {
            unsigned lo, hi;
            if (g < 64) {
                lo = __builtin_amdgcn_readlane((unsigned)rem0, g);
                hi = __builtin_amdgcn_readlane((unsigned)(rem0 >> 32), g);
            } else {
                lo = __builtin_amdgcn_readlane((unsigned)rem1, g - 64);
                hi = __builtin_amdgcn_readlane((unsigned)(rem1 >> 32), g - 64);
            }
            cur = ((unsigned long long)hi << 32) | lo;
        }
        const unsigned long long valid =
            (g == MASKW - 1) ? 0x0000FFFFFFFFFFFFull : ~0ull;   // 48 tail bits

        // ---- static speculative prefetch: compile-time indices only ----
        int sbit[SPEC];
        {
            unsigned long long t = (~cur) & valid;
            #pragma unroll
            for (int s = 0; s < SPEC; ++s) {
                sbit[s] = t ? __builtin_ctzll(t) : 64;
                t &= t - 1;
            }
        }
        unsigned long long sp0[SPEC], sp1[SPEC];
        #pragma unroll
        for (int s = 0; s < SPEC; ++s) {
            sp0[s] = 0ull; sp1[s] = 0ull;
            if (sbit[s] < 64) {                    // wave-uniform branch
                const unsigned long long* pr = mask + (size_t)(g * 64 + sbit[s]) * MW;
                sp0[s] = pr[lane];
                sp1[s] = (lane < MASKW - 64) ? pr[64 + lane] : 0ull;
            }
        }

        unsigned long long procd = 0ull;
        unsigned long long kb = 0ull;

        for (;;) {                                   // serial, pure ALU + reg ORs
            const unsigned long long nd = (~cur) & valid & ~procd;
            if (!nd) break;
            const int b = __builtin_ctzll(nd);
            procd |= (1ull << b);
            if (lane == 0 && cnt < 300) sKept[cnt] = g * 64 + b;
            ++cnt;
            kb |= (1ull << b);
            if (cnt >= 300) { done = 1; break; }
            const unsigned dlo = __builtin_amdgcn_readlane((unsigned)diag, b);
            const unsigned dhi = __builtin_amdgcn_readlane((unsigned)(diag >> 32), b);
            cur |= ((unsigned long long)dhi << 32) | dlo;
            // OR this kept row into remv: unrolled slot match (registers only)
            bool matched = false;
            #pragma unroll
            for (int s = 0; s < SPEC; ++s) {
                if (b == sbit[s]) {
                    rem0 |= sp0[s];
                    rem1 |= sp1[s];
                    matched = true;
                }
            }
            if (!matched) {                          // >SPEC overflow (rare)
                const unsigned long long* pr = mask + (size_t)(g * 64 + b) * MW;
                rem0 |= pr[lane];
                rem1 |= (lane < MASKW - 64) ? pr[64 + lane] : 0ull;
            }
        }
        if (lane == 0) sKeepW[g] = kb;
        diag = diag_next;
    }

    __syncthreads();                                 // publish sKeepW / sKept

    if (cnt < 300) {                                 // filler: unkept, asc index
        int c = cnt;
        for (int g = 0; g < MASKW && c < 300; ++g) {
            const unsigned long long valid =
                (g == MASKW - 1) ? 0x0000FFFFFFFFFFFFull : ~0ull;
            unsigned long long u = (~sKeepW[g]) & valid;
            while (u && c < 300) {
                const int b = __builtin_ctzll(u); u &= u - 1;
                if (lane == 0) sKept[c] = g * 64 + b;
                ++c;
            }
        }
    }
    __syncthreads();

    for (int s = lane; s < 300; s += 64) {
        const float4 b = sb[sKept[s]];
        out[s * 4 + 0] = b.x;
        out[s * 4 + 1] = b.y;
        out[s * 4 + 2] = b.z - b.x + 1.0f;
        out[s * 4 + 3] = b.w - b.y + 1.0f;
    }
}

// ---------------------------------------------------------------------------
extern "C" void kernel_launch(void* const* d_in, const int* in_sizes, int n_in,
                              void* d_out, int out_size, void* d_ws, size_t ws_size,
                              hipStream_t stream)
{
    (void)in_sizes; (void)n_in; (void)out_size; (void)ws_size;
    const float* x   = (const float*)d_in[0] + (size_t)7 * 512 * NPIX; // batch 7
    const float* cw3 = (const float*)d_in[1];
    const float* cb3 = (const float*)d_in[2];
    const float* rw  = (const float*)d_in[3];
    const float* rb  = (const float*)d_in[4];
    const float* clw = (const float*)d_in[5];
    const float* clb = (const float*)d_in[6];
    float* out = (float*)d_out;

    char* p = (char*)d_ws;
    auto alloc = [&](size_t n) { char* r = p; p += (n + 255) & ~(size_t)255; return r; };
    float*  part   = (float*)alloc((size_t)CS * 512 * NPIX * 4);  // 41 MB
    float*  feat   = (float*)alloc((size_t)512 * NPIX * 4);       // 5.12 MB
    float*  regcls = (float*)alloc((size_t)54 * NPIX * 4);        // 0.54 MB
    float4* boxes  = (float4*)alloc((size_t)NANCH * 16);          // 0.36 MB
    unsigned long long* keys = (unsigned long long*)alloc((size_t)NKEY * 8);
    int*    rank   = (int*)alloc((size_t)NANCH * 4);
    float4* sboxes = (float4*)alloc((size_t)PRE * 16);
    unsigned long long* mask = (unsigned long long*)alloc((size_t)PRE * MW * 8); // 4.6 MB

    hipMemsetAsync(rank, 0, (size_t)NANCH * 4, stream);
    conv3x3_part  <<<dim3(32, 20, CS), 128, 0, stream>>>(x, cw3, part);
    reduce_leaky  <<<5000, 256, 0, stream>>>(part, cb3, feat);
    conv1x1_heads <<<dim3(40, 3), 256, 0, stream>>>(feat, rw, rb, clw, clb, regcls);
    decodeK       <<<88, 256, 0, stream>>>(regcls, boxes, keys);
    rankK         <<<dim3(88, 8), 256, 0, stream>>>(keys, rank);
    scatterK      <<<88, 256, 0, stream>>>(boxes, rank, sboxes);
    nmsMaskK      <<<dim3(375, 4), 256, 0, stream>>>(sboxes, mask);
    nmsScanOutK   <<<1, 64, 0, stream>>>(mask, sboxes, out);
}

// Round 8
// 684.570 us; speedup vs baseline: 1.2911x; 1.2911x over previous
//
#include <hip/hip_runtime.h>

// ---------------------------------------------------------------------------
// RPN forward, MI355X. Only batch element 7 contributes to the output.
// transposeW -> conv3x3 v2 (lane=oc, coalesced weight vloads, LDS-broadcast
// inputs, 8 cin-split partials, px-major part) -> reduce+transpose+leaky ->
// 1x1 heads -> decode/score/key -> O(N^2) rank sort -> top-6000 ->
// NMS bitmask (reference's yy2=max bug replicated) -> word-serial scan ->
// 300x4 boxes. Deterministic fp32 everywhere (no float atomics).
// ---------------------------------------------------------------------------

#define NPIX 2500      // 50*50
#define NANCH 22500    // 2500*9
#define NKEY 22528     // NANCH padded to 88*256 (sentinel tail)
#define PRE 6000
#define MASKW 94       // ceil(6000/64) usable words
#define MW 96          // storage stride in words
#define JCHUNK 1536    // j-chunk for mask kernel (24 words)
#define CS 8           // cin splits for conv3x3
#define SPEC 16        // static speculative row-prefetch slots in scan

// ---------------- weight transpose: wt(oc,cin*9) -> wtT(cin*9,oc) ----------
// grid (72 ct-tiles, 8 oc-tiles), block 256. LDS-tiled, fully coalesced.
__global__ __launch_bounds__(256) void transposeW(
    const float* __restrict__ wt,   // (512, 4608)
    float* __restrict__ wtT)        // (4608, 512)
{
    __shared__ float T[64][65];
    const int tid = threadIdx.x;
    const int c   = tid & 63;
    const int r4  = tid >> 6;
    const int ct0 = blockIdx.x * 64;
    const int ocb = blockIdx.y * 64;
    #pragma unroll
    for (int i = 0; i < 16; ++i) {
        const int o = r4 + i * 4;
        T[o][c] = wt[(size_t)(ocb + o) * 4608 + ct0 + c];
    }
    __syncthreads();
    #pragma unroll
    for (int i = 0; i < 16; ++i) {
        const int ctl = r4 + i * 4;
        wtT[(size_t)(ct0 + ctl) * 512 + ocb + c] = T[c][ctl];
    }
}

// ---------------- conv 3x3 v2: lane = oc, wave = one image row -------------
// grid (8 ocGroups, 50 rows, 8 cin groups), block 64 (1 wave).
// Weights: 9 coalesced vloads/cin. Inputs: 3-row window in LDS, same-address
// ds_read broadcast (conflict-free). Rolling 3x3 column window in registers.
// part layout (CS, 2500, 512): per-px stores are 256B coalesced.
__global__ __launch_bounds__(64) void conv3x3_v2(
    const float* __restrict__ x,    // batch-7 base (512,50,50)
    const float* __restrict__ wtT,  // (4608, 512)
    float* __restrict__ part)       // (CS, 2500, 512)
{
    __shared__ float sRow[3 * 52];               // cols: 0 and 51 are zero pad
    const int lane = threadIdx.x;
    const int ocb  = blockIdx.x * 64;
    const int r    = blockIdx.y;                 // 0..49 (wave-uniform)
    const int cing = blockIdx.z * 64;

    const float m0 = (r > 0)  ? 1.0f : 0.0f;     // row r-1 valid
    const float m2 = (r < 49) ? 1.0f : 0.0f;     // row r+1 valid
    const int  sr0 = (r > 0)  ? r - 1 : 0;       // clamped source rows
    const int  sr2 = (r < 49) ? r + 1 : 49;

    // zero LDS pad columns once (cols 0 and 51 of each of 3 rows)
    if (lane < 6) {
        const int rr = lane >> 1;
        sRow[rr * 52 + (lane & 1) * 51] = 0.0f;
    }

    float acc[50];
    #pragma unroll
    for (int p = 0; p < 50; ++p) acc[p] = 0.f;

    for (int cin = 0; cin < 64; ++cin) {
        const float* xp = x + (size_t)(cing + cin) * NPIX;
        // stage 3 rows (masked) into LDS cols 1..50
        if (lane < 50) {
            const float v0 = xp[sr0 * 50 + lane] * m0;
            const float v1 = xp[r   * 50 + lane];
            const float v2 = xp[sr2 * 50 + lane] * m2;
            sRow[0 * 52 + 1 + lane] = v0;
            sRow[1 * 52 + 1 + lane] = v1;
            sRow[2 * 52 + 1 + lane] = v2;
        }
        // 9 coalesced weight loads (lane = oc)
        const float* wp = wtT + (size_t)(cin + cing) * 9 * 512 + ocb + lane;
        float w[9];
        #pragma unroll
        for (int t = 0; t < 9; ++t)
            w[t] = wp[(size_t)t * 512];

        // rolling 3x3 window, px fully unrolled
        float L0, L1, L2, C0, C1, C2, R0, R1, R2;
        L0 = 0.f; L1 = 0.f; L2 = 0.f;            // col 0 = pad
        C0 = sRow[0 * 52 + 1]; C1 = sRow[1 * 52 + 1]; C2 = sRow[2 * 52 + 1];
        #pragma unroll
        for (int p = 0; p < 50; ++p) {
            R0 = sRow[0 * 52 + p + 2];
            R1 = sRow[1 * 52 + p + 2];
            R2 = sRow[2 * 52 + p + 2];
            float a = acc[p];
            a = fmaf(w[0], L0, a); a = fmaf(w[1], C0, a); a = fmaf(w[2], R0, a);
            a = fmaf(w[3], L1, a); a = fmaf(w[4], C1, a); a = fmaf(w[5], R1, a);
            a = fmaf(w[6], L2, a); a = fmaf(w[7], C2, a); a = fmaf(w[8], R2, a);
            acc[p] = a;
            L0 = C0; L1 = C1; L2 = C2;
            C0 = R0; C1 = R1; C2 = R2;
        }
    }

    // coalesced stores: per px one 256B line
    float* dst = part + ((size_t)blockIdx.z * NPIX + r * 50) * 512 + ocb + lane;
    #pragma unroll
    for (int p = 0; p < 50; ++p)
        dst[(size_t)p * 512] = acc[p];
}

// ---------------- reduce partials + bias + leaky + transpose ---------------
// part (CS,2500,512) -> feat (512,2500). grid (40 px-tiles, 8 oc-tiles),
// block 256, LDS 64x65 tile.
__global__ __launch_bounds__(256) void reduce_leaky(
    const float* __restrict__ part, const float* __restrict__ bias,
    float* __restrict__ feat)
{
    __shared__ float T[64][65];
    const int tid = threadIdx.x;
    const int o   = tid & 63;
    const int r4  = tid >> 6;
    const int pt  = blockIdx.x;                  // px tile (64)
    const int ocb = blockIdx.y * 64;
    const float b = bias[ocb + o];
    #pragma unroll
    for (int i = 0; i < 16; ++i) {
        const int pl = r4 + i * 4;
        const int px = pt * 64 + pl;
        if (px < NPIX) {
            float s = 0.f;
            #pragma unroll
            for (int k = 0; k < CS; ++k)
                s += part[((size_t)k * NPIX + px) * 512 + ocb + o];
            s += b;
            s = (s >= 0.f) ? s : 0.01f * s;
            T[pl][o] = s;
        }
    }
    __syncthreads();
    const int pl = tid & 63;
    const int px = pt * 64 + pl;
    if (px < NPIX) {
        #pragma unroll
        for (int i = 0; i < 16; ++i) {
            const int ocl = r4 + i * 4;
            feat[(size_t)(ocb + ocl) * NPIX + px] = T[pl][ocl];
        }
    }
}

// ---------------- 1x1 heads: 4-wave cin split + LDS tree reduce ------------
__global__ __launch_bounds__(256) void conv1x1_heads(
    const float* __restrict__ feat,
    const float* __restrict__ rw, const float* __restrict__ rb,
    const float* __restrict__ cw, const float* __restrict__ cb,
    float* __restrict__ regcls)   // (54, 2500)
{
    __shared__ float sAcc[3][18][64];
    const int tid  = threadIdx.x;
    const int lane = tid & 63;
    const int wv   = tid >> 6;
    const int pix0 = blockIdx.x * 64 + lane;
    const bool act = (pix0 < NPIX);
    const int pix  = act ? pix0 : (NPIX - 1);
    const int chunk = blockIdx.y;
    const float* wb; const float* bb; int ocbase;
    if (chunk == 0)      { wb = rw;            bb = rb;      ocbase = 0;  }
    else if (chunk == 1) { wb = rw + 18 * 512; bb = rb + 18; ocbase = 18; }
    else                 { wb = cw;            bb = cb;      ocbase = 36; }

    float acc[18];
    #pragma unroll
    for (int k = 0; k < 18; ++k) acc[k] = 0.f;

    const int c0 = wv * 128;
    for (int cin = c0; cin < c0 + 128; ++cin) {
        const float v = feat[(size_t)cin * NPIX + pix];
        #pragma unroll
        for (int k = 0; k < 18; ++k)
            acc[k] = fmaf(wb[k * 512 + cin], v, acc[k]);
    }
    if (wv > 0) {
        #pragma unroll
        for (int k = 0; k < 18; ++k) sAcc[wv - 1][k][lane] = acc[k];
    }
    __syncthreads();
    if (wv == 0 && act) {
        #pragma unroll
        for (int k = 0; k < 18; ++k) {
            float s = acc[k];
            s += sAcc[0][k][lane];
            s += sAcc[1][k][lane];
            s += sAcc[2][k][lane];
            regcls[(size_t)(ocbase + k) * NPIX + pix] = s + bb[k];
        }
    }
}

// ---------------- decode: anchors, softmax score, sortable key -------------
__global__ __launch_bounds__(256) void decodeK(
    const float* __restrict__ regcls,
    float4* __restrict__ boxes,
    unsigned long long* __restrict__ keys)
{
    const int i = blockIdx.x * 256 + threadIdx.x;
    if (i >= NANCH) {
        if (i < NKEY) keys[i] = 0xFFFFFFFFFFFFFFFFull;  // sentinel: > all keys
        return;
    }
    const int pos = i / 9;
    const int a   = i - pos * 9;
    const int hh  = pos / 50;
    const int wwp = pos - hh * 50;
    const int r = a / 3, s = a - r * 3;

    const float base_s[3] = {128.f, 256.f, 512.f};
    const float sq [3] = {0.70710678118654752440f, 1.0f, 1.41421356237309504880f};
    const float sqi[3] = {1.41421356237309504880f, 1.0f, 0.70710678118654752440f};
    const float hs = base_s[s] * sq[r];
    const float ws = base_s[s] * sqi[r];
    const float cx = (float)(hh * 16 + 8);    // cx indexed by h (reference quirk)
    const float cy = (float)(wwp * 16 + 8);
    const float ax = cx - ws * 0.5f;
    const float ay = cy - hs * 0.5f;

    const float pr0 = regcls[(size_t)(a * 4 + 0) * NPIX + pos];
    const float pr1 = regcls[(size_t)(a * 4 + 1) * NPIX + pos];
    const float pr2 = regcls[(size_t)(a * 4 + 2) * NPIX + pos];
    const float pr3 = regcls[(size_t)(a * 4 + 3) * NPIX + pos];
    const float c0  = regcls[(size_t)(36 + a * 2 + 0) * NPIX + pos];
    const float c1  = regcls[(size_t)(36 + a * 2 + 1) * NPIX + pos];

    const float m  = fmaxf(c0, c1);
    const float e0 = expf(c0 - m);
    const float e1 = expf(c1 - m);
    const float score = e1 / (e0 + e1);

    const float t0 = pr0 + ax;
    const float t1 = pr1 + ay;
    const float hi = 799.0f;
    const float rx1 = fminf(fmaxf(t0, 0.f), hi);
    const float ry1 = fminf(fmaxf(t1, 0.f), hi);
    const float rx2 = fminf(fmaxf((t0 + pr2) + ws, 0.f), hi);
    const float ry2 = fminf(fmaxf((t1 + pr3) + hs, 0.f), hi);
    const float bw = pr2 + ws;
    const float bh = pr3 + hs;
    const bool valid = (bw >= 16.f) && (bh >= 16.f);
    const float sc = valid ? score : -__builtin_inff();

    unsigned u = __float_as_uint(sc);
    u = (u & 0x80000000u) ? ~u : (u | 0x80000000u);  // monotone ascending map
    const unsigned k32 = ~u;                          // descending score
    keys[i]  = ((unsigned long long)k32 << 32) | (unsigned)i;  // tie: asc index
    boxes[i] = make_float4(rx1, ry1, rx2, ry2);
}

// ---------------- O(N^2) rank (stable argsort position) --------------------
__global__ __launch_bounds__(256) void rankK(
    const unsigned long long* __restrict__ keys, int* __restrict__ rank)
{
    const int i = blockIdx.x * 256 + threadIdx.x;
    const unsigned long long my = (i < NANCH) ? keys[i] : 0ull;
    const unsigned long long* kj = keys + blockIdx.y * 2816;
    int cnt = 0;
    for (int t = 0; t < 2816; t += 8) {
        #pragma unroll
        for (int q = 0; q < 8; ++q)
            cnt += (kj[t + q] < my) ? 1 : 0;
    }
    if (i < NANCH) atomicAdd(&rank[i], cnt);
}

__global__ __launch_bounds__(256) void scatterK(
    const float4* __restrict__ boxes, const int* __restrict__ rank,
    float4* __restrict__ sboxes)
{
    const int i = blockIdx.x * 256 + threadIdx.x;
    if (i < NANCH) {
        const int r = rank[i];
        if (r < PRE) sboxes[r] = boxes[i];
    }
}

// ---------------- NMS suppression bitmask (reference bug replicated) -------
__global__ __launch_bounds__(256) void nmsMaskK(
    const float4* __restrict__ sb, unsigned long long* __restrict__ mask)
{
    __shared__ float sx1[JCHUNK], sy1[JCHUNK], sx2[JCHUNK], sy2[JCHUNK], sar[JCHUNK];
    const int tid = threadIdx.x;
    const int jbase = blockIdx.y * JCHUNK;
    for (int t = tid; t < JCHUNK; t += 256) {
        const int j = jbase + t;
        if (j < PRE) {
            const float4 b = sb[j];
            sx1[t] = b.x; sy1[t] = b.y; sx2[t] = b.z; sy2[t] = b.w;
            sar[t] = (b.z - b.x + 1.f) * (b.w - b.y + 1.f);
        } else {
            sx1[t] = 0.f; sy1[t] = 0.f; sx2[t] = -1.f; sy2[t] = 0.f; sar[t] = 0.f;
        }
    }
    __syncthreads();
    const int i = blockIdx.x * 16 + (tid >> 4);
    const float4 bi = sb[i];
    const float x1 = bi.x, y1 = bi.y, x2 = bi.z, y2 = bi.w;
    const float ar = (x2 - x1 + 1.f) * (y2 - y1 + 1.f);
    for (int w = (tid & 15); w < 24; w += 16) {
        unsigned long long bits = 0ull;
        const int l0 = w * 64;
        for (int u = 0; u < 64; ++u) {
            const int j = jbase + l0 + u;
            if (j > i && j < PRE) {
                const int l = l0 + u;
                const float xx1 = fmaxf(x1, sx1[l]);
                const float yy1 = fmaxf(y1, sy1[l]);
                const float xx2 = fminf(x2, sx2[l]);
                const float yy2 = fmaxf(y2, sy2[l]);        // reference bug: max
                const float wv = fmaxf(0.f, xx2 - xx1 + 1.f);
                const float hv = fmaxf(0.f, yy2 - yy1 + 1.f);
                const float inter = wv * hv;
                const float ov = inter / ((ar + sar[l]) - inter);  // precise div
                if (ov > 0.7f) bits |= (1ull << u);
            }
        }
        mask[(size_t)i * MW + blockIdx.y * 24 + w] = bits;
    }
}

// ---------------- word-serial NMS scan + output (single wave) --------------
__global__ __launch_bounds__(64) void nmsScanOutK(
    const unsigned long long* __restrict__ mask,
    const float4* __restrict__ sb,
    float* __restrict__ out)
{
    __shared__ int sKept[300];
    __shared__ unsigned long long sKeepW[MASKW];
    const int lane = threadIdx.x;

    unsigned long long rem0 = 0ull, rem1 = 0ull;   // lane l: words l, 64+l
    int cnt = 0;
    int done = 0;

    unsigned long long diag = mask[(size_t)lane * MW + 0];   // block 0 diag

    for (int g = 0; g < MASKW && !done; ++g) {
        unsigned long long diag_next = 0ull;
        if (g + 1 < MASKW) {
            const int r2 = (g + 1) * 64 + lane;
            if (r2 < PRE) diag_next = mask[(size_t)r2 * MW + (g + 1)];
        }
        unsigned long long cur;
        {
            unsigned lo, hi;
            if (g < 64) {
                lo = __builtin_amdgcn_readlane((unsigned)rem0, g);
                hi = __builtin_amdgcn_readlane((unsigned)(rem0 >> 32), g);
            } else {
                lo = __builtin_amdgcn_readlane((unsigned)rem1, g - 64);
                hi = __builtin_amdgcn_readlane((unsigned)(rem1 >> 32), g - 64);
            }
            cur = ((unsigned long long)hi << 32) | lo;
        }
        const unsigned long long valid =
            (g == MASKW - 1) ? 0x0000FFFFFFFFFFFFull : ~0ull;   // 48 tail bits

        // static speculative prefetch: compile-time indices only
        int sbit[SPEC];
        {
            unsigned long long t = (~cur) & valid;
            #pragma unroll
            for (int s = 0; s < SPEC; ++s) {
                sbit[s] = t ? __builtin_ctzll(t) : 64;
                t &= t - 1;
            }
        }
        unsigned long long sp0[SPEC], sp1[SPEC];
        #pragma unroll
        for (int s = 0; s < SPEC; ++s) {
            sp0[s] = 0ull; sp1[s] = 0ull;
            if (sbit[s] < 64) {
                const unsigned long long* pr = mask + (size_t)(g * 64 + sbit[s]) * MW;
                sp0[s] = pr[lane];
                sp1[s] = (lane < MASKW - 64) ? pr[64 + lane] : 0ull;
            }
        }

        unsigned long long procd = 0ull;
        unsigned long long kb = 0ull;

        for (;;) {                                   // serial, pure ALU + reg ORs
            const unsigned long long nd = (~cur) & valid & ~procd;
            if (!nd) break;
            const int b = __builtin_ctzll(nd);
            procd |= (1ull << b);
            if (lane == 0 && cnt < 300) sKept[cnt] = g * 64 + b;
            ++cnt;
            kb |= (1ull << b);
            if (cnt >= 300) { done = 1; break; }
            const unsigned dlo = __builtin_amdgcn_readlane((unsigned)diag, b);
            const unsigned dhi = __builtin_amdgcn_readlane((unsigned)(diag >> 32), b);
            cur |= ((unsigned long long)dhi << 32) | dlo;
            bool matched = false;
            #pragma unroll
            for (int s = 0; s < SPEC; ++s) {
                if (b == sbit[s]) {
                    rem0 |= sp0[s];
                    rem1 |= sp1[s];
                    matched = true;
                }
            }
            if (!matched) {
                const unsigned long long* pr = mask + (size_t)(g * 64 + b) * MW;
                rem0 |= pr[lane];
                rem1 |= (lane < MASKW - 64) ? pr[64 + lane] : 0ull;
            }
        }
        if (lane == 0) sKeepW[g] = kb;
        diag = diag_next;
    }

    __syncthreads();

    if (cnt < 300) {                                 // filler: unkept, asc index
        int c = cnt;
        for (int g = 0; g < MASKW && c < 300; ++g) {
            const unsigned long long valid =
                (g == MASKW - 1) ? 0x0000FFFFFFFFFFFFull : ~0ull;
            unsigned long long u = (~sKeepW[g]) & valid;
            while (u && c < 300) {
                const int b = __builtin_ctzll(u); u &= u - 1;
                if (lane == 0) sKept[c] = g * 64 + b;
                ++c;
            }
        }
    }
    __syncthreads();

    for (int s = lane; s < 300; s += 64) {
        const float4 b = sb[sKept[s]];
        out[s * 4 + 0] = b.x;
        out[s * 4 + 1] = b.y;
        out[s * 4 + 2] = b.z - b.x + 1.0f;
        out[s * 4 + 3] = b.w - b.y + 1.0f;
    }
}

// ---------------------------------------------------------------------------
extern "C" void kernel_launch(void* const* d_in, const int* in_sizes, int n_in,
                              void* d_out, int out_size, void* d_ws, size_t ws_size,
                              hipStream_t stream)
{
    (void)in_sizes; (void)n_in; (void)out_size; (void)ws_size;
    const float* x   = (const float*)d_in[0] + (size_t)7 * 512 * NPIX; // batch 7
    const float* cw3 = (const float*)d_in[1];
    const float* cb3 = (const float*)d_in[2];
    const float* rw  = (const float*)d_in[3];
    const float* rb  = (const float*)d_in[4];
    const float* clw = (const float*)d_in[5];
    const float* clb = (const float*)d_in[6];
    float* out = (float*)d_out;

    char* p = (char*)d_ws;
    auto alloc = [&](size_t n) { char* r = p; p += (n + 255) & ~(size_t)255; return r; };
    float*  part   = (float*)alloc((size_t)CS * NPIX * 512 * 4);  // 41 MB
    float*  wtT    = (float*)alloc((size_t)4608 * 512 * 4);       // 9.4 MB
    float*  feat   = (float*)alloc((size_t)512 * NPIX * 4);       // 5.12 MB
    float*  regcls = (float*)alloc((size_t)54 * NPIX * 4);        // 0.54 MB
    float4* boxes  = (float4*)alloc((size_t)NANCH * 16);          // 0.36 MB
    unsigned long long* keys = (unsigned long long*)alloc((size_t)NKEY * 8);
    int*    rank   = (int*)alloc((size_t)NANCH * 4);
    float4* sboxes = (float4*)alloc((size_t)PRE * 16);
    unsigned long long* mask = (unsigned long long*)alloc((size_t)PRE * MW * 8); // 4.6 MB

    hipMemsetAsync(rank, 0, (size_t)NANCH * 4, stream);
    transposeW    <<<dim3(72, 8), 256, 0, stream>>>(cw3, wtT);
    conv3x3_v2    <<<dim3(8, 50, CS), 64, 0, stream>>>(x, wtT, part);
    reduce_leaky  <<<dim3(40, 8), 256, 0, stream>>>(part, cb3, feat);
    conv1x1_heads <<<dim3(40, 3), 256, 0, stream>>>(feat, rw, rb, clw, clb, regcls);
    decodeK       <<<88, 256, 0, stream>>>(regcls, boxes, keys);
    rankK         <<<dim3(88, 8), 256, 0, stream>>>(keys, rank);
    scatterK      <<<88, 256, 0, stream>>>(boxes, rank, sboxes);
    nmsMaskK      <<<dim3(375, 4), 256, 0, stream>>>(sboxes, mask);
    nmsScanOutK   <<<1, 64, 0, stream>>>(mask, sboxes, out);
}

// Round 9
// 676.288 us; speedup vs baseline: 1.3069x; 1.0122x over previous
//
#include <hip/hip_runtime.h>

// ---------------------------------------------------------------------------
// RPN forward, MI355X. Only batch element 7 contributes to the output.
// transposeW -> conv3x3 v2 (lane=oc, coalesced weight vloads, b128 LDS
// broadcast reads, 8 cin-split partials, px-major part) -> reduce+leaky ->
// 1x1 heads -> decode/score/key -> O(N^2) rank sort -> top-6000 ->
// NMS bitmask (reference's yy2=max bug replicated) -> word-serial scan ->
// 300x4 boxes. Deterministic fp32 everywhere (no float atomics).
// ---------------------------------------------------------------------------

#define NPIX 2500      // 50*50
#define NANCH 22500    // 2500*9
#define NKEY 22528     // NANCH padded to 88*256 (sentinel tail)
#define PRE 6000
#define MASKW 94       // ceil(6000/64) usable words
#define MW 96          // storage stride in words
#define JCHUNK 1536    // j-chunk for mask kernel (24 words)
#define CS 8           // cin splits for conv3x3
#define SPEC 16        // static speculative row-prefetch slots in scan

// ---------------- weight transpose: wt(oc,cin*9) -> wtT(cin*9,oc) ----------
__global__ __launch_bounds__(256) void transposeW(
    const float* __restrict__ wt,   // (512, 4608)
    float* __restrict__ wtT)        // (4608, 512)
{
    __shared__ float T[64][65];
    const int tid = threadIdx.x;
    const int c   = tid & 63;
    const int r4  = tid >> 6;
    const int ct0 = blockIdx.x * 64;
    const int ocb = blockIdx.y * 64;
    #pragma unroll
    for (int i = 0; i < 16; ++i) {
        const int o = r4 + i * 4;
        T[o][c] = wt[(size_t)(ocb + o) * 4608 + ct0 + c];
    }
    __syncthreads();
    #pragma unroll
    for (int i = 0; i < 16; ++i) {
        const int ctl = r4 + i * 4;
        wtT[(size_t)(ct0 + ctl) * 512 + ocb + c] = T[c][ctl];
    }
}

// ---------------- conv 3x3 v2b: lane = oc, wave = one image row ------------
// grid (8 ocGroups, 50 rows, 8 cin groups), block 64 (1 wave).
// Weights: 9 coalesced vloads/cin. Inputs: 3-row window in LDS (row stride
// 56 floats, 16B aligned), read as 13 ds_read_b128 blocks per row per cin
// (39 total vs 150 scalar reads) with a 2-column register carry.
// part layout (CS, 2500, 512): per-px stores are 256B coalesced.
__global__ __launch_bounds__(64) void conv3x3_v2(
    const float* __restrict__ x,    // batch-7 base (512,50,50)
    const float* __restrict__ wtT,  // (4608, 512)
    float* __restrict__ part)       // (CS, 2500, 512)
{
    __shared__ __align__(16) float sRow[3 * 56];  // col0 + cols51..55 are pad
    const int lane = threadIdx.x;
    const int ocb  = blockIdx.x * 64;
    const int r    = blockIdx.y;                 // 0..49 (wave-uniform)
    const int cing = blockIdx.z * 64;

    const float m0 = (r > 0)  ? 1.0f : 0.0f;     // row r-1 valid
    const float m2 = (r < 49) ? 1.0f : 0.0f;     // row r+1 valid
    const int  sr0 = (r > 0)  ? r - 1 : 0;       // clamped source rows
    const int  sr2 = (r < 49) ? r + 1 : 49;

    // zero pad columns once: each row cols {0, 51..55}
    if (lane < 18) {
        const int rr = lane / 6;
        const int cc = lane - rr * 6;            // 0..5
        const int col = (cc == 0) ? 0 : (50 + cc);
        sRow[rr * 56 + col] = 0.0f;
    }

    float acc[50];
    #pragma unroll
    for (int p = 0; p < 50; ++p) acc[p] = 0.f;

    for (int cin = 0; cin < 64; ++cin) {
        const float* xp = x + (size_t)(cing + cin) * NPIX;
        // stage 3 rows (masked) into LDS storage cols 1..50
        if (lane < 50) {
            sRow[0 * 56 + 1 + lane] = xp[sr0 * 50 + lane] * m0;
            sRow[1 * 56 + 1 + lane] = xp[r   * 50 + lane];
            sRow[2 * 56 + 1 + lane] = xp[sr2 * 50 + lane] * m2;
        }
        // 9 coalesced weight loads (lane = oc)
        const float* wp = wtT + (size_t)(cing + cin) * 9 * 512 + ocb + lane;
        float w0 = wp[0 * 512], w1 = wp[1 * 512], w2 = wp[2 * 512];
        float w3 = wp[3 * 512], w4 = wp[4 * 512], w5 = wp[5 * 512];
        float w6 = wp[6 * 512], w7 = wp[7 * 512], w8 = wp[8 * 512];

        const float4* R0 = (const float4*)(sRow + 0 * 56);
        const float4* R1 = (const float4*)(sRow + 1 * 56);
        const float4* R2 = (const float4*)(sRow + 2 * 56);

        // px p uses storage cols p..p+2. Block B holds cols 4B..4B+3.
        float4 q0, q1, q2;                        // previous block (carry .z/.w)
        q0 = q1 = q2 = make_float4(0.f, 0.f, 0.f, 0.f);
        #pragma unroll
        for (int B = 0; B < 13; ++B) {
            const float4 n0 = R0[B];
            const float4 n1 = R1[B];
            const float4 n2 = R2[B];
            if (B > 0) {
                const int p = 4 * B - 2;
                float a = acc[p];
                a = fmaf(w0, q0.z, a); a = fmaf(w1, q0.w, a); a = fmaf(w2, n0.x, a);
                a = fmaf(w3, q1.z, a); a = fmaf(w4, q1.w, a); a = fmaf(w5, n1.x, a);
                a = fmaf(w6, q2.z, a); a = fmaf(w7, q2.w, a); a = fmaf(w8, n2.x, a);
                acc[p] = a;
                float b = acc[p + 1];
                b = fmaf(w0, q0.w, b); b = fmaf(w1, n0.x, b); b = fmaf(w2, n0.y, b);
                b = fmaf(w3, q1.w, b); b = fmaf(w4, n1.x, b); b = fmaf(w5, n1.y, b);
                b = fmaf(w6, q2.w, b); b = fmaf(w7, n2.x, b); b = fmaf(w8, n2.y, b);
                acc[p + 1] = b;
            }
            {
                const int p = 4 * B;              // px 4B, 4B+1 (<= 49)
                float a = acc[p];
                a = fmaf(w0, n0.x, a); a = fmaf(w1, n0.y, a); a = fmaf(w2, n0.z, a);
                a = fmaf(w3, n1.x, a); a = fmaf(w4, n1.y, a); a = fmaf(w5, n1.z, a);
                a = fmaf(w6, n2.x, a); a = fmaf(w7, n2.y, a); a = fmaf(w8, n2.z, a);
                acc[p] = a;
                float b = acc[p + 1];
                b = fmaf(w0, n0.y, b); b = fmaf(w1, n0.z, b); b = fmaf(w2, n0.w, b);
                b = fmaf(w3, n1.y, b); b = fmaf(w4, n1.z, b); b = fmaf(w5, n1.w, b);
                b = fmaf(w6, n2.y, b); b = fmaf(w7, n2.z, b); b = fmaf(w8, n2.w, b);
                acc[p + 1] = b;
            }
            q0 = n0; q1 = n1; q2 = n2;
        }
    }

    // coalesced stores: per px one 256B line
    float* dst = part + ((size_t)blockIdx.z * NPIX + r * 50) * 512 + ocb + lane;
    #pragma unroll
    for (int p = 0; p < 50; ++p)
        dst[(size_t)p * 512] = acc[p];
}

// ---------------- reduce partials + bias + leaky + transpose ---------------
__global__ __launch_bounds__(256) void reduce_leaky(
    const float* __restrict__ part, const float* __restrict__ bias,
    float* __restrict__ feat)
{
    __shared__ float T[64][65];
    const int tid = threadIdx.x;
    const int o   = tid & 63;
    const int r4  = tid >> 6;
    const int pt  = blockIdx.x;                  // px tile (64)
    const int ocb = blockIdx.y * 64;
    const float b = bias[ocb + o];
    #pragma unroll
    for (int i = 0; i < 16; ++i) {
        const int pl = r4 + i * 4;
        const int px = pt * 64 + pl;
        if (px < NPIX) {
            float s = 0.f;
            #pragma unroll
            for (int k = 0; k < CS; ++k)
                s += part[((size_t)k * NPIX + px) * 512 + ocb + o];
            s += b;
            s = (s >= 0.f) ? s : 0.01f * s;
            T[pl][o] = s;
        }
    }
    __syncthreads();
    const int pl = tid & 63;
    const int px = pt * 64 + pl;
    if (px < NPIX) {
        #pragma unroll
        for (int i = 0; i < 16; ++i) {
            const int ocl = r4 + i * 4;
            feat[(size_t)(ocb + ocl) * NPIX + px] = T[pl][ocl];
        }
    }
}

// ---------------- 1x1 heads: 4-wave cin split + LDS tree reduce ------------
__global__ __launch_bounds__(256) void conv1x1_heads(
    const float* __restrict__ feat,
    const float* __restrict__ rw, const float* __restrict__ rb,
    const float* __restrict__ cw, const float* __restrict__ cb,
    float* __restrict__ regcls)   // (54, 2500)
{
    __shared__ float sAcc[3][18][64];
    const int tid  = threadIdx.x;
    const int lane = tid & 63;
    const int wv   = tid >> 6;
    const int pix0 = blockIdx.x * 64 + lane;
    const bool act = (pix0 < NPIX);
    const int pix  = act ? pix0 : (NPIX - 1);
    const int chunk = blockIdx.y;
    const float* wb; const float* bb; int ocbase;
    if (chunk == 0)      { wb = rw;            bb = rb;      ocbase = 0;  }
    else if (chunk == 1) { wb = rw + 18 * 512; bb = rb + 18; ocbase = 18; }
    else                 { wb = cw;            bb = cb;      ocbase = 36; }

    float acc[18];
    #pragma unroll
    for (int k = 0; k < 18; ++k) acc[k] = 0.f;

    const int c0 = wv * 128;
    for (int cin = c0; cin < c0 + 128; ++cin) {
        const float v = feat[(size_t)cin * NPIX + pix];
        #pragma unroll
        for (int k = 0; k < 18; ++k)
            acc[k] = fmaf(wb[k * 512 + cin], v, acc[k]);
    }
    if (wv > 0) {
        #pragma unroll
        for (int k = 0; k < 18; ++k) sAcc[wv - 1][k][lane] = acc[k];
    }
    __syncthreads();
    if (wv == 0 && act) {
        #pragma unroll
        for (int k = 0; k < 18; ++k) {
            float s = acc[k];
            s += sAcc[0][k][lane];
            s += sAcc[1][k][lane];
            s += sAcc[2][k][lane];
            regcls[(size_t)(ocbase + k) * NPIX + pix] = s + bb[k];
        }
    }
}

// ---------------- decode: anchors, softmax score, sortable key -------------
__global__ __launch_bounds__(256) void decodeK(
    const float* __restrict__ regcls,
    float4* __restrict__ boxes,
    unsigned long long* __restrict__ keys)
{
    const int i = blockIdx.x * 256 + threadIdx.x;
    if (i >= NANCH) {
        if (i < NKEY) keys[i] = 0xFFFFFFFFFFFFFFFFull;  // sentinel: > all keys
        return;
    }
    const int pos = i / 9;
    const int a   = i - pos * 9;
    const int hh  = pos / 50;
    const int wwp = pos - hh * 50;
    const int r = a / 3, s = a - r * 3;

    const float base_s[3] = {128.f, 256.f, 512.f};
    const float sq [3] = {0.70710678118654752440f, 1.0f, 1.41421356237309504880f};
    const float sqi[3] = {1.41421356237309504880f, 1.0f, 0.70710678118654752440f};
    const float hs = base_s[s] * sq[r];
    const float ws = base_s[s] * sqi[r];
    const float cx = (float)(hh * 16 + 8);    // cx indexed by h (reference quirk)
    const float cy = (float)(wwp * 16 + 8);
    const float ax = cx - ws * 0.5f;
    const float ay = cy - hs * 0.5f;

    const float pr0 = regcls[(size_t)(a * 4 + 0) * NPIX + pos];
    const float pr1 = regcls[(size_t)(a * 4 + 1) * NPIX + pos];
    const float pr2 = regcls[(size_t)(a * 4 + 2) * NPIX + pos];
    const float pr3 = regcls[(size_t)(a * 4 + 3) * NPIX + pos];
    const float c0  = regcls[(size_t)(36 + a * 2 + 0) * NPIX + pos];
    const float c1  = regcls[(size_t)(36 + a * 2 + 1) * NPIX + pos];

    const float m  = fmaxf(c0, c1);
    const float e0 = expf(c0 - m);
    const float e1 = expf(c1 - m);
    const float score = e1 / (e0 + e1);

    const float t0 = pr0 + ax;
    const float t1 = pr1 + ay;
    const float hi = 799.0f;
    const float rx1 = fminf(fmaxf(t0, 0.f), hi);
    const float ry1 = fminf(fmaxf(t1, 0.f), hi);
    const float rx2 = fminf(fmaxf((t0 + pr2) + ws, 0.f), hi);
    const float ry2 = fminf(fmaxf((t1 + pr3) + hs, 0.f), hi);
    const float bw = pr2 + ws;
    const float bh = pr3 + hs;
    const bool valid = (bw >= 16.f) && (bh >= 16.f);
    const float sc = valid ? score : -__builtin_inff();

    unsigned u = __float_as_uint(sc);
    u = (u & 0x80000000u) ? ~u : (u | 0x80000000u);  // monotone ascending map
    const unsigned k32 = ~u;                          // descending score
    keys[i]  = ((unsigned long long)k32 << 32) | (unsigned)i;  // tie: asc index
    boxes[i] = make_float4(rx1, ry1, rx2, ry2);
}

// ---------------- O(N^2) rank (stable argsort position) --------------------
__global__ __launch_bounds__(256) void rankK(
    const unsigned long long* __restrict__ keys, int* __restrict__ rank)
{
    const int i = blockIdx.x * 256 + threadIdx.x;
    const unsigned long long my = (i < NANCH) ? keys[i] : 0ull;
    const unsigned long long* kj = keys + blockIdx.y * 2816;
    int cnt = 0;
    for (int t = 0; t < 2816; t += 8) {
        #pragma unroll
        for (int q = 0; q < 8; ++q)
            cnt += (kj[t + q] < my) ? 1 : 0;
    }
    if (i < NANCH) atomicAdd(&rank[i], cnt);
}

__global__ __launch_bounds__(256) void scatterK(
    const float4* __restrict__ boxes, const int* __restrict__ rank,
    float4* __restrict__ sboxes)
{
    const int i = blockIdx.x * 256 + threadIdx.x;
    if (i < NANCH) {
        const int r = rank[i];
        if (r < PRE) sboxes[r] = boxes[i];
    }
}

// ---------------- NMS suppression bitmask (reference bug replicated) -------
__global__ __launch_bounds__(256) void nmsMaskK(
    const float4* __restrict__ sb, unsigned long long* __restrict__ mask)
{
    __shared__ float sx1[JCHUNK], sy1[JCHUNK], sx2[JCHUNK], sy2[JCHUNK], sar[JCHUNK];
    const int tid = threadIdx.x;
    const int jbase = blockIdx.y * JCHUNK;
    for (int t = tid; t < JCHUNK; t += 256) {
        const int j = jbase + t;
        if (j < PRE) {
            const float4 b = sb[j];
            sx1[t] = b.x; sy1[t] = b.y; sx2[t] = b.z; sy2[t] = b.w;
            sar[t] = (b.z - b.x + 1.f) * (b.w - b.y + 1.f);
        } else {
            sx1[t] = 0.f; sy1[t] = 0.f; sx2[t] = -1.f; sy2[t] = 0.f; sar[t] = 0.f;
        }
    }
    __syncthreads();
    const int i = blockIdx.x * 16 + (tid >> 4);
    const float4 bi = sb[i];
    const float x1 = bi.x, y1 = bi.y, x2 = bi.z, y2 = bi.w;
    const float ar = (x2 - x1 + 1.f) * (y2 - y1 + 1.f);
    for (int w = (tid & 15); w < 24; w += 16) {
        unsigned long long bits = 0ull;
        const int l0 = w * 64;
        for (int u = 0; u < 64; ++u) {
            const int j = jbase + l0 + u;
            if (j > i && j < PRE) {
                const int l = l0 + u;
                const float xx1 = fmaxf(x1, sx1[l]);
                const float yy1 = fmaxf(y1, sy1[l]);
                const float xx2 = fminf(x2, sx2[l]);
                const float yy2 = fmaxf(y2, sy2[l]);        // reference bug: max
                const float wv = fmaxf(0.f, xx2 - xx1 + 1.f);
                const float hv = fmaxf(0.f, yy2 - yy1 + 1.f);
                const float inter = wv * hv;
                const float ov = inter / ((ar + sar[l]) - inter);  // precise div
                if (ov > 0.7f) bits |= (1ull << u);
            }
        }
        mask[(size_t)i * MW + blockIdx.y * 24 + w] = bits;
    }
}

// ---------------- word-serial NMS scan + output (single wave) --------------
__global__ __launch_bounds__(64) void nmsScanOutK(
    const unsigned long long* __restrict__ mask,
    const float4* __restrict__ sb,
    float* __restrict__ out)
{
    __shared__ int sKept[300];
    __shared__ unsigned long long sKeepW[MASKW];
    const int lane = threadIdx.x;

    unsigned long long rem0 = 0ull, rem1 = 0ull;   // lane l: words l, 64+l
    int cnt = 0;
    int done = 0;

    unsigned long long diag = mask[(size_t)lane * MW + 0];   // block 0 diag

    for (int g = 0; g < MASKW && !done; ++g) {
        unsigned long long diag_next = 0ull;
        if (g + 1 < MASKW) {
            const int r2 = (g + 1) * 64 + lane;
            if (r2 < PRE) diag_next = mask[(size_t)r2 * MW + (g + 1)];
        }
        unsigned long long cur;
        {
            unsigned lo, hi;
            if (g < 64) {
                lo = __builtin_amdgcn_readlane((unsigned)rem0, g);
                hi = __builtin_amdgcn_readlane((unsigned)(rem0 >> 32), g);
            } else {
                lo = __builtin_amdgcn_readlane((unsigned)rem1, g - 64);
                hi = __builtin_amdgcn_readlane((unsigned)(rem1 >> 32), g - 64);
            }
            cur = ((unsigned long long)hi << 32) | lo;
        }
        const unsigned long long valid =
            (g == MASKW - 1) ? 0x0000FFFFFFFFFFFFull : ~0ull;   // 48 tail bits

        // static speculative prefetch: compile-time indices only
        int sbit[SPEC];
        {
            unsigned long long t = (~cur) & valid;
            #pragma unroll
            for (int s = 0; s < SPEC; ++s) {
                sbit[s] = t ? __builtin_ctzll(t) : 64;
                t &= t - 1;
            }
        }
        unsigned long long sp0[SPEC], sp1[SPEC];
        #pragma unroll
        for (int s = 0; s < SPEC; ++s) {
            sp0[s] = 0ull; sp1[s] = 0ull;
            if (sbit[s] < 64) {
                const unsigned long long* pr = mask + (size_t)(g * 64 + sbit[s]) * MW;
                sp0[s] = pr[lane];
                sp1[s] = (lane < MASKW - 64) ? pr[64 + lane] : 0ull;
            }
        }

        unsigned long long procd = 0ull;
        unsigned long long kb = 0ull;

        for (;;) {                                   // serial, pure ALU + reg ORs
            const unsigned long long nd = (~cur) & valid & ~procd;
            if (!nd) break;
            const int b = __builtin_ctzll(nd);
            procd |= (1ull << b);
            if (lane == 0 && cnt < 300) sKept[cnt] = g * 64 + b;
            ++cnt;
            kb |= (1ull << b);
            if (cnt >= 300) { done = 1; break; }
            const unsigned dlo = __builtin_amdgcn_readlane((unsigned)diag, b);
            const unsigned dhi = __builtin_amdgcn_readlane((unsigned)(diag >> 32), b);
            cur |= ((unsigned long long)dhi << 32) | dlo;
            bool matched = false;
            #pragma unroll
            for (int s = 0; s < SPEC; ++s) {
                if (b == sbit[s]) {
                    rem0 |= sp0[s];
                    rem1 |= sp1[s];
                    matched = true;
                }
            }
            if (!matched) {
                const unsigned long long* pr = mask + (size_t)(g * 64 + b) * MW;
                rem0 |= pr[lane];
                rem1 |= (lane < MASKW - 64) ? pr[64 + lane] : 0ull;
            }
        }
        if (lane == 0) sKeepW[g] = kb;
        diag = diag_next;
    }

    __syncthreads();

    if (cnt < 300) {                                 // filler: unkept, asc index
        int c = cnt;
        for (int g = 0; g < MASKW && c < 300; ++g) {
            const unsigned long long valid =
                (g == MASKW - 1) ? 0x0000FFFFFFFFFFFFull : ~0ull;
            unsigned long long u = (~sKeepW[g]) & valid;
            while (u && c < 300) {
                const int b = __builtin_ctzll(u); u &= u - 1;
                if (lane == 0) sKept[c] = g * 64 + b;
                ++c;
            }
        }
    }
    __syncthreads();

    for (int s = lane; s < 300; s += 64) {
        const float4 b = sb[sKept[s]];
        out[s * 4 + 0] = b.x;
        out[s * 4 + 1] = b.y;
        out[s * 4 + 2] = b.z - b.x + 1.0f;
        out[s * 4 + 3] = b.w - b.y + 1.0f;
    }
}

// ---------------------------------------------------------------------------
extern "C" void kernel_launch(void* const* d_in, const int* in_sizes, int n_in,
                              void* d_out, int out_size, void* d_ws, size_t ws_size,
                              hipStream_t stream)
{
    (void)in_sizes; (void)n_in; (void)out_size; (void)ws_size;
    const float* x   = (const float*)d_in[0] + (size_t)7 * 512 * NPIX; // batch 7
    const float* cw3 = (const float*)d_in[1];
    const float* cb3 = (const float*)d_in[2];
    const float* rw  = (const float*)d_in[3];
    const float* rb  = (const float*)d_in[4];
    const float* clw = (const float*)d_in[5];
    const float* clb = (const float*)d_in[6];
    float* out = (float*)d_out;

    char* p = (char*)d_ws;
    auto alloc = [&](size_t n) { char* r = p; p += (n + 255) & ~(size_t)255; return r; };
    float*  part   = (float*)alloc((size_t)CS * NPIX * 512 * 4);  // 41 MB
    float*  wtT    = (float*)alloc((size_t)4608 * 512 * 4);       // 9.4 MB
    float*  feat   = (float*)alloc((size_t)512 * NPIX * 4);       // 5.12 MB
    float*  regcls = (float*)alloc((size_t)54 * NPIX * 4);        // 0.54 MB
    float4* boxes  = (float4*)alloc((size_t)NANCH * 16);          // 0.36 MB
    unsigned long long* keys = (unsigned long long*)alloc((size_t)NKEY * 8);
    int*    rank   = (int*)alloc((size_t)NANCH * 4);
    float4* sboxes = (float4*)alloc((size_t)PRE * 16);
    unsigned long long* mask = (unsigned long long*)alloc((size_t)PRE * MW * 8); // 4.6 MB

    hipMemsetAsync(rank, 0, (size_t)NANCH * 4, stream);
    transposeW    <<<dim3(72, 8), 256, 0, stream>>>(cw3, wtT);
    conv3x3_v2    <<<dim3(8, 50, CS), 64, 0, stream>>>(x, wtT, part);
    reduce_leaky  <<<dim3(40, 8), 256, 0, stream>>>(part, cb3, feat);
    conv1x1_heads <<<dim3(40, 3), 256, 0, stream>>>(feat, rw, rb, clw, clb, regcls);
    decodeK       <<<88, 256, 0, stream>>>(regcls, boxes, keys);
    rankK         <<<dim3(88, 8), 256, 0, stream>>>(keys, rank);
    scatterK      <<<88, 256, 0, stream>>>(boxes, rank, sboxes);
    nmsMaskK      <<<dim3(375, 4), 256, 0, stream>>>(sboxes, mask);
    nmsScanOutK   <<<1, 64, 0, stream>>>(mask, sboxes, out);
}

// Round 11
// 623.992 us; speedup vs baseline: 1.4165x; 1.0838x over previous
//
#include <hip/hip_runtime.h>

// ---------------------------------------------------------------------------
// RPN forward, MI355X. Only batch element 7 contributes to the output.
// transposeW -> conv3x3 v3 (lane=2oc, coalesced weight vloads, LDS-broadcast
// inputs, 8 cin-split partials, px-major part) -> reduce+leaky -> 1x1 heads
// -> decode/score/key -> O(N^2) rank sort -> top-6000 -> NMS bitmask
// (reference's yy2=max bug replicated) -> word-serial scan (ALU in-block
// loop + batched kept-row loads) -> 300x4 boxes. Deterministic fp32.
// ---------------------------------------------------------------------------

#define NPIX 2500      // 50*50
#define NANCH 22500    // 2500*9
#define NKEY 22528     // NANCH padded to 88*256 (sentinel tail)
#define PRE 6000
#define MASKW 94       // ceil(6000/64) usable words
#define MW 96          // storage stride in words
#define JCHUNK 1536    // j-chunk for mask kernel (24 words)
#define CS 8           // cin splits for conv3x3
#define KSLOT 8        // static kept-row load slots per block in scan

// ---------------- weight transpose: wt(oc,cin*9) -> wtT(cin*9,oc) ----------
__global__ __launch_bounds__(256) void transposeW(
    const float* __restrict__ wt,   // (512, 4608)
    float* __restrict__ wtT)        // (4608, 512)
{
    __shared__ float T[64][65];
    const int tid = threadIdx.x;
    const int c   = tid & 63;
    const int r4  = tid >> 6;
    const int ct0 = blockIdx.x * 64;
    const int ocb = blockIdx.y * 64;
    #pragma unroll
    for (int i = 0; i < 16; ++i) {
        const int o = r4 + i * 4;
        T[o][c] = wt[(size_t)(ocb + o) * 4608 + ct0 + c];
    }
    __syncthreads();
    #pragma unroll
    for (int i = 0; i < 16; ++i) {
        const int ctl = r4 + i * 4;
        wtT[(size_t)(ct0 + ctl) * 512 + ocb + c] = T[c][ctl];
    }
}

// ---------------- conv 3x3 v3: lane = 2 oc (o, o+64), wave = one row -------
// grid (4 ocGroups, 50 rows, 8 cin groups), block 64 (1 wave).
// Per cin: 18 coalesced weight loads, 3-row LDS window (b128 broadcast
// reads), 50 px x 2 oc x 9 taps = 900 FMA -> 2x arithmetic intensity vs v2.
__global__ __launch_bounds__(64) void conv3x3_v3(
    const float* __restrict__ x,    // batch-7 base (512,50,50)
    const float* __restrict__ wtT,  // (4608, 512)
    float* __restrict__ part)       // (CS, 2500, 512)
{
    __shared__ __align__(16) float sRow[3 * 56];  // col0 + cols51..55 are pad
    const int lane = threadIdx.x;
    const int ocb  = blockIdx.x * 128;
    const int r    = blockIdx.y;                 // 0..49 (wave-uniform)
    const int cing = blockIdx.z * 64;

    const float m0 = (r > 0)  ? 1.0f : 0.0f;
    const float m2 = (r < 49) ? 1.0f : 0.0f;
    const int  sr0 = (r > 0)  ? r - 1 : 0;
    const int  sr2 = (r < 49) ? r + 1 : 49;

    if (lane < 18) {                              // zero pad cols {0, 51..55}
        const int rr = lane / 6;
        const int cc = lane - rr * 6;
        const int col = (cc == 0) ? 0 : (50 + cc);
        sRow[rr * 56 + col] = 0.0f;
    }

    float accA[50], accB[50];
    #pragma unroll
    for (int p = 0; p < 50; ++p) { accA[p] = 0.f; accB[p] = 0.f; }

    for (int cin = 0; cin < 64; ++cin) {
        const float* xp = x + (size_t)(cing + cin) * NPIX;
        if (lane < 50) {
            sRow[0 * 56 + 1 + lane] = xp[sr0 * 50 + lane] * m0;
            sRow[1 * 56 + 1 + lane] = xp[r   * 50 + lane];
            sRow[2 * 56 + 1 + lane] = xp[sr2 * 50 + lane] * m2;
        }
        const float* wp = wtT + (size_t)(cing + cin) * 9 * 512 + ocb + lane;
        float wA[9], wB[9];
        #pragma unroll
        for (int t = 0; t < 9; ++t) {
            wA[t] = wp[(size_t)t * 512];
            wB[t] = wp[(size_t)t * 512 + 64];
        }

        const float4* R0 = (const float4*)(sRow + 0 * 56);
        const float4* R1 = (const float4*)(sRow + 1 * 56);
        const float4* R2 = (const float4*)(sRow + 2 * 56);

        float4 q0, q1, q2;
        q0 = q1 = q2 = make_float4(0.f, 0.f, 0.f, 0.f);
        #pragma unroll
        for (int B = 0; B < 13; ++B) {
            const float4 n0 = R0[B];
            const float4 n1 = R1[B];
            const float4 n2 = R2[B];
            if (B > 0) {
                const int p = 4 * B - 2;
                {
                    float a = accA[p], b = accB[p];
                    a = fmaf(wA[0], q0.z, a); a = fmaf(wA[1], q0.w, a); a = fmaf(wA[2], n0.x, a);
                    a = fmaf(wA[3], q1.z, a); a = fmaf(wA[4], q1.w, a); a = fmaf(wA[5], n1.x, a);
                    a = fmaf(wA[6], q2.z, a); a = fmaf(wA[7], q2.w, a); a = fmaf(wA[8], n2.x, a);
                    b = fmaf(wB[0], q0.z, b); b = fmaf(wB[1], q0.w, b); b = fmaf(wB[2], n0.x, b);
                    b = fmaf(wB[3], q1.z, b); b = fmaf(wB[4], q1.w, b); b = fmaf(wB[5], n1.x, b);
                    b = fmaf(wB[6], q2.z, b); b = fmaf(wB[7], q2.w, b); b = fmaf(wB[8], n2.x, b);
                    accA[p] = a; accB[p] = b;
                }
                {
                    float a = accA[p + 1], b = accB[p + 1];
                    a = fmaf(wA[0], q0.w, a); a = fmaf(wA[1], n0.x, a); a = fmaf(wA[2], n0.y, a);
                    a = fmaf(wA[3], q1.w, a); a = fmaf(wA[4], n1.x, a); a = fmaf(wA[5], n1.y, a);
                    a = fmaf(wA[6], q2.w, a); a = fmaf(wA[7], n2.x, a); a = fmaf(wA[8], n2.y, a);
                    b = fmaf(wB[0], q0.w, b); b = fmaf(wB[1], n0.x, b); b = fmaf(wB[2], n0.y, b);
                    b = fmaf(wB[3], q1.w, b); b = fmaf(wB[4], n1.x, b); b = fmaf(wB[5], n1.y, b);
                    b = fmaf(wB[6], q2.w, b); b = fmaf(wB[7], n2.x, b); b = fmaf(wB[8], n2.y, b);
                    accA[p + 1] = a; accB[p + 1] = b;
                }
            }
            {
                const int p = 4 * B;
                {
                    float a = accA[p], b = accB[p];
                    a = fmaf(wA[0], n0.x, a); a = fmaf(wA[1], n0.y, a); a = fmaf(wA[2], n0.z, a);
                    a = fmaf(wA[3], n1.x, a); a = fmaf(wA[4], n1.y, a); a = fmaf(wA[5], n1.z, a);
                    a = fmaf(wA[6], n2.x, a); a = fmaf(wA[7], n2.y, a); a = fmaf(wA[8], n2.z, a);
                    b = fmaf(wB[0], n0.x, b); b = fmaf(wB[1], n0.y, b); b = fmaf(wB[2], n0.z, b);
                    b = fmaf(wB[3], n1.x, b); b = fmaf(wB[4], n1.y, b); b = fmaf(wB[5], n1.z, b);
                    b = fmaf(wB[6], n2.x, b); b = fmaf(wB[7], n2.y, b); b = fmaf(wB[8], n2.z, b);
                    accA[p] = a; accB[p] = b;
                }
                {
                    float a = accA[p + 1], b = accB[p + 1];
                    a = fmaf(wA[0], n0.y, a); a = fmaf(wA[1], n0.z, a); a = fmaf(wA[2], n0.w, a);
                    a = fmaf(wA[3], n1.y, a); a = fmaf(wA[4], n1.z, a); a = fmaf(wA[5], n1.w, a);
                    a = fmaf(wA[6], n2.y, a); a = fmaf(wA[7], n2.z, a); a = fmaf(wA[8], n2.w, a);
                    b = fmaf(wB[0], n0.y, b); b = fmaf(wB[1], n0.z, b); b = fmaf(wB[2], n0.w, b);
                    b = fmaf(wB[3], n1.y, b); b = fmaf(wB[4], n1.z, b); b = fmaf(wB[5], n1.w, b);
                    b = fmaf(wB[6], n2.y, b); b = fmaf(wB[7], n2.z, b); b = fmaf(wB[8], n2.w, b);
                    accA[p + 1] = a; accB[p + 1] = b;
                }
            }
            q0 = n0; q1 = n1; q2 = n2;
        }
    }

    float* dst = part + ((size_t)blockIdx.z * NPIX + r * 50) * 512 + ocb + lane;
    #pragma unroll
    for (int p = 0; p < 50; ++p) {
        dst[(size_t)p * 512]      = accA[p];
        dst[(size_t)p * 512 + 64] = accB[p];
    }
}

// ---------------- reduce partials + bias + leaky + transpose ---------------
__global__ __launch_bounds__(256) void reduce_leaky(
    const float* __restrict__ part, const float* __restrict__ bias,
    float* __restrict__ feat)
{
    __shared__ float T[64][65];
    const int tid = threadIdx.x;
    const int o   = tid & 63;
    const int r4  = tid >> 6;
    const int pt  = blockIdx.x;
    const int ocb = blockIdx.y * 64;
    const float b = bias[ocb + o];
    #pragma unroll
    for (int i = 0; i < 16; ++i) {
        const int pl = r4 + i * 4;
        const int px = pt * 64 + pl;
        if (px < NPIX) {
            float s = 0.f;
            #pragma unroll
            for (int k = 0; k < CS; ++k)
                s += part[((size_t)k * NPIX + px) * 512 + ocb + o];
            s += b;
            s = (s >= 0.f) ? s : 0.01f * s;
            T[pl][o] = s;
        }
    }
    __syncthreads();
    const int pl = tid & 63;
    const int px = pt * 64 + pl;
    if (px < NPIX) {
        #pragma unroll
        for (int i = 0; i < 16; ++i) {
            const int ocl = r4 + i * 4;
            feat[(size_t)(ocb + ocl) * NPIX + px] = T[pl][ocl];
        }
    }
}

// ---------------- 1x1 heads: 4-wave cin split + LDS tree reduce ------------
__global__ __launch_bounds__(256) void conv1x1_heads(
    const float* __restrict__ feat,
    const float* __restrict__ rw, const float* __restrict__ rb,
    const float* __restrict__ cw, const float* __restrict__ cb,
    float* __restrict__ regcls)   // (54, 2500)
{
    __shared__ float sAcc[3][18][64];
    const int tid  = threadIdx.x;
    const int lane = tid & 63;
    const int wv   = tid >> 6;
    const int pix0 = blockIdx.x * 64 + lane;
    const bool act = (pix0 < NPIX);
    const int pix  = act ? pix0 : (NPIX - 1);
    const int chunk = blockIdx.y;
    const float* wb; const float* bb; int ocbase;
    if (chunk == 0)      { wb = rw;            bb = rb;      ocbase = 0;  }
    else if (chunk == 1) { wb = rw + 18 * 512; bb = rb + 18; ocbase = 18; }
    else                 { wb = cw;            bb = cb;      ocbase = 36; }

    float acc[18];
    #pragma unroll
    for (int k = 0; k < 18; ++k) acc[k] = 0.f;

    const int c0 = wv * 128;
    for (int cin = c0; cin < c0 + 128; ++cin) {
        const float v = feat[(size_t)cin * NPIX + pix];
        #pragma unroll
        for (int k = 0; k < 18; ++k)
            acc[k] = fmaf(wb[k * 512 + cin], v, acc[k]);
    }
    if (wv > 0) {
        #pragma unroll
        for (int k = 0; k < 18; ++k) sAcc[wv - 1][k][lane] = acc[k];
    }
    __syncthreads();
    if (wv == 0 && act) {
        #pragma unroll
        for (int k = 0; k < 18; ++k) {
            float s = acc[k];
            s += sAcc[0][k][lane];
            s += sAcc[1][k][lane];
            s += sAcc[2][k][lane];
            regcls[(size_t)(ocbase + k) * NPIX + pix] = s + bb[k];
        }
    }
}

// ---------------- decode: anchors, softmax score, sortable key -------------
__global__ __launch_bounds__(256) void decodeK(
    const float* __restrict__ regcls,
    float4* __restrict__ boxes,
    unsigned long long* __restrict__ keys)
{
    const int i = blockIdx.x * 256 + threadIdx.x;
    if (i >= NANCH) {
        if (i < NKEY) keys[i] = 0xFFFFFFFFFFFFFFFFull;  // sentinel: > all keys
        return;
    }
    const int pos = i / 9;
    const int a   = i - pos * 9;
    const int hh  = pos / 50;
    const int wwp = pos - hh * 50;
    const int r = a / 3, s = a - r * 3;

    const float base_s[3] = {128.f, 256.f, 512.f};
    const float sq [3] = {0.70710678118654752440f, 1.0f, 1.41421356237309504880f};
    const float sqi[3] = {1.41421356237309504880f, 1.0f, 0.70710678118654752440f};
    const float hs = base_s[s] * sq[r];
    const float ws = base_s[s] * sqi[r];
    const float cx = (float)(hh * 16 + 8);    // cx indexed by h (reference quirk)
    const float cy = (float)(wwp * 16 + 8);
    const float ax = cx - ws * 0.5f;
    const float ay = cy - hs * 0.5f;

    const float pr0 = regcls[(size_t)(a * 4 + 0) * NPIX + pos];
    const float pr1 = regcls[(size_t)(a * 4 + 1) * NPIX + pos];
    const float pr2 = regcls[(size_t)(a * 4 + 2) * NPIX + pos];
    const float pr3 = regcls[(size_t)(a * 4 + 3) * NPIX + pos];
    const float c0  = regcls[(size_t)(36 + a * 2 + 0) * NPIX + pos];
    const float c1  = regcls[(size_t)(36 + a * 2 + 1) * NPIX + pos];

    const float m  = fmaxf(c0, c1);
    const float e0 = expf(c0 - m);
    const float e1 = expf(c1 - m);
    const float score = e1 / (e0 + e1);

    const float t0 = pr0 + ax;
    const float t1 = pr1 + ay;
    const float hi = 799.0f;
    const float rx1 = fminf(fmaxf(t0, 0.f), hi);
    const float ry1 = fminf(fmaxf(t1, 0.f), hi);
    const float rx2 = fminf(fmaxf((t0 + pr2) + ws, 0.f), hi);
    const float ry2 = fminf(fmaxf((t1 + pr3) + hs, 0.f), hi);
    const float bw = pr2 + ws;
    const float bh = pr3 + hs;
    const bool valid = (bw >= 16.f) && (bh >= 16.f);
    const float sc = valid ? score : -__builtin_inff();

    unsigned u = __float_as_uint(sc);
    u = (u & 0x80000000u) ? ~u : (u | 0x80000000u);  // monotone ascending map
    const unsigned k32 = ~u;                          // descending score
    keys[i]  = ((unsigned long long)k32 << 32) | (unsigned)i;  // tie: asc index
    boxes[i] = make_float4(rx1, ry1, rx2, ry2);
}

// ---------------- O(N^2) rank (stable argsort position) --------------------
__global__ __launch_bounds__(256) void rankK(
    const unsigned long long* __restrict__ keys, int* __restrict__ rank)
{
    const int i = blockIdx.x * 256 + threadIdx.x;
    const unsigned long long my = (i < NANCH) ? keys[i] : 0ull;
    const unsigned long long* kj = keys + blockIdx.y * 2816;
    int cnt = 0;
    for (int t = 0; t < 2816; t += 8) {
        #pragma unroll
        for (int q = 0; q < 8; ++q)
            cnt += (kj[t + q] < my) ? 1 : 0;
    }
    if (i < NANCH) atomicAdd(&rank[i], cnt);
}

__global__ __launch_bounds__(256) void scatterK(
    const float4* __restrict__ boxes, const int* __restrict__ rank,
    float4* __restrict__ sboxes)
{
    const int i = blockIdx.x * 256 + threadIdx.x;
    if (i < NANCH) {
        const int r = rank[i];
        if (r < PRE) sboxes[r] = boxes[i];
    }
}

// ---------------- NMS suppression bitmask (reference bug replicated) -------
__global__ __launch_bounds__(256) void nmsMaskK(
    const float4* __restrict__ sb, unsigned long long* __restrict__ mask)
{
    __shared__ float sx1[JCHUNK], sy1[JCHUNK], sx2[JCHUNK], sy2[JCHUNK], sar[JCHUNK];
    const int tid = threadIdx.x;
    const int jbase = blockIdx.y * JCHUNK;
    for (int t = tid; t < JCHUNK; t += 256) {
        const int j = jbase + t;
        if (j < PRE) {
            const float4 b = sb[j];
            sx1[t] = b.x; sy1[t] = b.y; sx2[t] = b.z; sy2[t] = b.w;
            sar[t] = (b.z - b.x + 1.f) * (b.w - b.y + 1.f);
        } else {
            sx1[t] = 0.f; sy1[t] = 0.f; sx2[t] = -1.f; sy2[t] = 0.f; sar[t] = 0.f;
        }
    }
    __syncthreads();
    const int i = blockIdx.x * 16 + (tid >> 4);
    const float4 bi = sb[i];
    const float x1 = bi.x, y1 = bi.y, x2 = bi.z, y2 = bi.w;
    const float ar = (x2 - x1 + 1.f) * (y2 - y1 + 1.f);
    for (int w = (tid & 15); w < 24; w += 16) {
        unsigned long long bits = 0ull;
        const int l0 = w * 64;
        for (int u = 0; u < 64; ++u) {
            const int j = jbase + l0 + u;
            if (j > i && j < PRE) {
                const int l = l0 + u;
                const float xx1 = fmaxf(x1, sx1[l]);
                const float yy1 = fmaxf(y1, sy1[l]);
                const float xx2 = fminf(x2, sx2[l]);
                const float yy2 = fmaxf(y2, sy2[l]);        // reference bug: max
                const float wv = fmaxf(0.f, xx2 - xx1 + 1.f);
                const float hv = fmaxf(0.f, yy2 - yy1 + 1.f);
                const float inter = wv * hv;
                const float ov = inter / ((ar + sar[l]) - inter);  // precise div
                if (ov > 0.7f) bits |= (1ull << u);
            }
        }
        mask[(size_t)i * MW + blockIdx.y * 24 + w] = bits;
    }
}

// ---------------- word-serial NMS scan + output (single wave) --------------
// Per 64-candidate block g: (1) pure-ALU in-block loop using ONLY the diag
// word (every iteration keeps exactly one box; suppression via diag
// readlanes); (2) batched loads of the ~3 actually-kept rows (<=KSLOT static
// slots + rare overflow), one wait, OR into register-resident rem.
__global__ __launch_bounds__(64) void nmsScanOutK(
    const unsigned long long* __restrict__ mask,
    const float4* __restrict__ sb,
    float* __restrict__ out)
{
    __shared__ int sKept[300];
    __shared__ unsigned long long sKeepW[MASKW];
    const int lane = threadIdx.x;

    unsigned long long rem0 = 0ull, rem1 = 0ull;   // lane l: words l, 64+l
    int cnt = 0;
    int done = 0;

    unsigned long long diag = mask[(size_t)lane * MW + 0];   // block 0 diag

    for (int g = 0; g < MASKW && !done; ++g) {
        // prefetch next block's diagonal word (overlaps this block's work)
        unsigned long long diag_next = 0ull;
        if (g + 1 < MASKW) {
            const int r2 = (g + 1) * 64 + lane;
            if (r2 < PRE) diag_next = mask[(size_t)r2 * MW + (g + 1)];
        }
        // initial suppression word for this block (broadcast from rem)
        unsigned long long cur;
        {
            unsigned lo, hi;
            if (g < 64) {
                lo = __builtin_amdgcn_readlane((unsigned)rem0, g);
                hi = __builtin_amdgcn_readlane((unsigned)(rem0 >> 32), g);
            } else {
                lo = __builtin_amdgcn_readlane((unsigned)rem1, g - 64);
                hi = __builtin_amdgcn_readlane((unsigned)(rem1 >> 32), g - 64);
            }
            cur = ((unsigned long long)hi << 32) | lo;
        }
        const unsigned long long valid =
            (g == MASKW - 1) ? 0x0000FFFFFFFFFFFFull : ~0ull;   // 48 tail bits

        // ---- in-block serial loop: pure ALU, zero memory ops ----
        unsigned long long kb = 0ull;
        for (;;) {
            const unsigned long long nd = (~cur) & valid;
            if (!nd) break;
            const int b = __builtin_ctzll(nd);     // unsuppressed => KEPT
            if (lane == 0 && cnt < 300) sKept[cnt] = g * 64 + b;
            ++cnt;
            kb |= (1ull << b);
            if (cnt >= 300) { done = 1; break; }
            const unsigned dlo = __builtin_amdgcn_readlane((unsigned)diag, b);
            const unsigned dhi = __builtin_amdgcn_readlane((unsigned)(diag >> 32), b);
            cur |= (1ull << b) | (((unsigned long long)dhi << 32) | dlo);
        }
        if (lane == 0) sKeepW[g] = kb;

        // ---- batched kept-row loads: OR their full rows into rem ----
        if (!done && kb) {
            int kbit[KSLOT];
            unsigned long long t = kb;
            #pragma unroll
            for (int s = 0; s < KSLOT; ++s) {
                kbit[s] = t ? __builtin_ctzll(t) : 64;
                t &= t - 1;
            }
            unsigned long long a0 = 0ull, a1 = 0ull;
            #pragma unroll
            for (int s = 0; s < KSLOT; ++s) {
                if (kbit[s] < 64) {                // wave-uniform branch
                    const unsigned long long* pr =
                        mask + (size_t)(g * 64 + kbit[s]) * MW;
                    a0 |= pr[lane];
                    a1 |= (lane < MASKW - 64) ? pr[64 + lane] : 0ull;
                }
            }
            while (t) {                             // >KSLOT overflow (rare)
                const int b = __builtin_ctzll(t); t &= t - 1;
                const unsigned long long* pr = mask + (size_t)(g * 64 + b) * MW;
                a0 |= pr[lane];
                a1 |= (lane < MASKW - 64) ? pr[64 + lane] : 0ull;
            }
            rem0 |= a0;
            rem1 |= a1;
        }
        diag = diag_next;
    }

    __syncthreads();

    if (cnt < 300) {                                 // filler: unkept, asc index
        int c = cnt;
        for (int g = 0; g < MASKW && c < 300; ++g) {
            const unsigned long long valid =
                (g == MASKW - 1) ? 0x0000FFFFFFFFFFFFull : ~0ull;
            unsigned long long u = (~sKeepW[g]) & valid;
            while (u && c < 300) {
                const int b = __builtin_ctzll(u); u &= u - 1;
                if (lane == 0) sKept[c] = g * 64 + b;
                ++c;
            }
        }
    }
    __syncthreads();

    for (int s = lane; s < 300; s += 64) {
        const float4 b = sb[sKept[s]];
        out[s * 4 + 0] = b.x;
        out[s * 4 + 1] = b.y;
        out[s * 4 + 2] = b.z - b.x + 1.0f;
        out[s * 4 + 3] = b.w - b.y + 1.0f;
    }
}

// ---------------------------------------------------------------------------
extern "C" void kernel_launch(void* const* d_in, const int* in_sizes, int n_in,
                              void* d_out, int out_size, void* d_ws, size_t ws_size,
                              hipStream_t stream)
{
    (void)in_sizes; (void)n_in; (void)out_size; (void)ws_size;
    const float* x   = (const float*)d_in[0] + (size_t)7 * 512 * NPIX; // batch 7
    const float* cw3 = (const float*)d_in[1];
    const float* cb3 = (const float*)d_in[2];
    const float* rw  = (const float*)d_in[3];
    const float* rb  = (const float*)d_in[4];
    const float* clw = (const float*)d_in[5];
    const float* clb = (const float*)d_in[6];
    float* out = (float*)d_out;

    char* p = (char*)d_ws;
    auto alloc = [&](size_t n) { char* r = p; p += (n + 255) & ~(size_t)255; return r; };
    float*  part   = (float*)alloc((size_t)CS * NPIX * 512 * 4);  // 41 MB
    float*  wtT    = (float*)alloc((size_t)4608 * 512 * 4);       // 9.4 MB
    float*  feat   = (float*)alloc((size_t)512 * NPIX * 4);       // 5.12 MB
    float*  regcls = (float*)alloc((size_t)54 * NPIX * 4);        // 0.54 MB
    float4* boxes  = (float4*)alloc((size_t)NANCH * 16);          // 0.36 MB
    unsigned long long* keys = (unsigned long long*)alloc((size_t)NKEY * 8);
    int*    rank   = (int*)alloc((size_t)NANCH * 4);
    float4* sboxes = (float4*)alloc((size_t)PRE * 16);
    unsigned long long* mask = (unsigned long long*)alloc((size_t)PRE * MW * 8); // 4.6 MB

    hipMemsetAsync(rank, 0, (size_t)NANCH * 4, stream);
    transposeW    <<<dim3(72, 8), 256, 0, stream>>>(cw3, wtT);
    conv3x3_v3    <<<dim3(4, 50, CS), 64, 0, stream>>>(x, wtT, part);
    reduce_leaky  <<<dim3(40, 8), 256, 0, stream>>>(part, cb3, feat);
    conv1x1_heads <<<dim3(40, 3), 256, 0, stream>>>(feat, rw, rb, clw, clb, regcls);
    decodeK       <<<88, 256, 0, stream>>>(regcls, boxes, keys);
    rankK         <<<dim3(88, 8), 256, 0, stream>>>(keys, rank);
    scatterK      <<<88, 256, 0, stream>>>(boxes, rank, sboxes);
    nmsMaskK      <<<dim3(375, 4), 256, 0, stream>>>(sboxes, mask);
    nmsScanOutK   <<<1, 64, 0, stream>>>(mask, sboxes, out);
}